// Round 1
// baseline (1347.595 us; speedup 1.0000x reference)
//
#include <hip/hip_runtime.h>

// UpSampling: out[row][0:N] = 0, out[row][N+e] = 0.5*(data[row][e0] + data[row][e1])
// rows = B*C = 512, N = 100000, E = 200000, all f32.
//
// Key structure: XCD row-affinity swizzle. MI355X round-robins blocks over 8 XCDs
// (xcd = dispatch_index % 8). We remap so each XCD owns a contiguous 64-row slice
// and walks its rows sequentially -> each XCD's L2 (4 MiB) holds the current row's
// data (400 KB) + the shared edge list (1.6 MB) resident. Gathers hit L2 instead of
// replicating row data across all 8 XCD L2s and thrashing to LLC.

constexpr int B_ = 4, C_ = 128, N_ = 100000, E_ = 200000;
constexpr int ROWS = B_ * C_;            // 512
constexpr long long W = N_ + E_;         // 300000 floats per output row
constexpr int NQ = N_ / 4;               // 25000 float4 zero-stores per row
constexpr int MT = E_ / 8;               // 25000 mid threads per row (8 edges each)
constexpr int ZT = NQ / 2;               // 12500 zero threads per row (2 float4 each)
constexpr int MB = (MT + 255) / 256;     // 98 mid blocks per row
constexpr int ZB = (ZT + 255) / 256;     // 49 zero blocks per row
constexpr int P  = MB + ZB;              // 147 blocks per row
constexpr int NXCD = 8;
constexpr int RPG  = ROWS / NXCD;        // 64 rows per XCD
// total grid = P * ROWS = 75264 blocks; 75264 % 8 == 0 -> swizzle is bijective.

typedef float  vf4 __attribute__((ext_vector_type(4)));
typedef int    vi4 __attribute__((ext_vector_type(4)));

__global__ __launch_bounds__(256) void upsample_kernel(
    const float* __restrict__ data,
    const vi4*   __restrict__ e4,     // edges as int4: 2 edges per vi4
    float*       __restrict__ out)
{
    // XCD-affinity decode: hardware assigns xcd = blockIdx.x % 8 (round-robin).
    const int flat = blockIdx.x;
    const int xcd  = flat & 7;
    const int j    = flat >> 3;        // per-XCD work index, 0 .. RPG*P-1
    const int rg   = j / P;            // row within this XCD's slice, 0..63
    const int bx   = j - rg * P;       // block within row, 0..146
    const int row  = xcd * RPG + rg;

    float* __restrict__ orow = out + (size_t)row * (size_t)W;
    const int tid = threadIdx.x;

    if (bx < MB) {
        // mids: 8 edges per thread -> 16 gathers in flight -> 2 float4 stores
        const int t = bx * 256 + tid;
        if (t < MT) {
            const float* __restrict__ drow = data + (size_t)row * (size_t)N_;
            vi4 a = e4[4 * t + 0];
            vi4 b = e4[4 * t + 1];
            vi4 c = e4[4 * t + 2];
            vi4 d = e4[4 * t + 3];
            vf4 m0, m1;
            m0.x = 0.5f * (drow[a.x] + drow[a.y]);
            m0.y = 0.5f * (drow[a.z] + drow[a.w]);
            m0.z = 0.5f * (drow[b.x] + drow[b.y]);
            m0.w = 0.5f * (drow[b.z] + drow[b.w]);
            m1.x = 0.5f * (drow[c.x] + drow[c.y]);
            m1.y = 0.5f * (drow[c.z] + drow[c.w]);
            m1.z = 0.5f * (drow[d.x] + drow[d.y]);
            m1.w = 0.5f * (drow[d.z] + drow[d.w]);
            vf4* mq = (vf4*)(orow + N_);
            __builtin_nontemporal_store(m0, mq + 2 * t);
            __builtin_nontemporal_store(m1, mq + 2 * t + 1);
        }
    } else {
        // zero-fill head: 2 float4 per thread (N % 8 == 0, offsets 16B-aligned)
        const int t = (bx - MB) * 256 + tid;
        if (t < ZT) {
            vf4 z = (vf4)(0.f);
            vf4* zq = (vf4*)orow;
            __builtin_nontemporal_store(z, zq + 2 * t);
            __builtin_nontemporal_store(z, zq + 2 * t + 1);
        }
    }
}

extern "C" void kernel_launch(void* const* d_in, const int* in_sizes, int n_in,
                              void* d_out, int out_size, void* d_ws, size_t ws_size,
                              hipStream_t stream) {
    const float* data  = (const float*)d_in[0];
    const vi4*   edges = (const vi4*)d_in[1];
    float*       out   = (float*)d_out;

    dim3 grid(P * ROWS);   // 1D grid, 75264 blocks
    upsample_kernel<<<grid, 256, 0, stream>>>(data, edges, out);
}